// Round 1
// 639.143 us; speedup vs baseline: 1.0524x; 1.0524x over previous
//
#include <hip/hip_runtime.h>
#include <math.h>

// Segment-prefix max:
//   for segment i (rows [start_i, start_i + sizes_i)), out[i][:] =
//   max over rows [start_i, start_i + sizes_i - window + 1) of x.
// Shapes (fixed by setup_inputs): x = [2048*512, 128] fp32, sizes = [2048] int,
// window = 3. Memory-bound: ~535 MB read / launch -> ~85 us floor @ 6.3 TB/s.
//
// R1 change vs baseline: per-block PHASE ROTATION of the row loop.
// Theory: all 2048 blocks stream 256-KiB-aligned segments in lockstep ->
// at any instant all active addresses are congruent mod the HBM channel
// interleave period -> channel camping convoy -> ~1.6 TB/s. Rotating each
// block's start row by (seg & 63) * 8 rows (4 KiB granularity, 64 phases
// spanning the full 256 KiB segment) decorrelates the streams. Max is
// order-independent, so rotation is free. Loads are also marked
// non-temporal (zero reuse; avoid L2 allocate).

#define BLOCK 256

typedef float f32x4 __attribute__((ext_vector_type(4)));

__device__ __forceinline__ f32x4 fmax4v(f32x4 a, f32x4 b) {
    f32x4 r;
    r.x = fmaxf(a.x, b.x);
    r.y = fmaxf(a.y, b.y);
    r.z = fmaxf(a.z, b.z);
    r.w = fmaxf(a.w, b.w);
    return r;
}

__global__ __launch_bounds__(BLOCK)
void seg_prefix_max_kernel(const float* __restrict__ x,
                           const int* __restrict__ sizes,
                           const int* __restrict__ wptr,
                           float* __restrict__ out,
                           int n_seg, int D) {
    const int seg = blockIdx.x;
    if (seg >= n_seg) return;
    const int tid = threadIdx.x;
    const int w   = *wptr;

    // ---- start_i = sum(sizes[0..seg)) : strided sum + LDS tree reduce ----
    __shared__ int red[BLOCK];
    int partial = 0;
    for (int j = tid; j < seg; j += BLOCK) partial += sizes[j];
    red[tid] = partial;
    __syncthreads();
    for (int s = BLOCK / 2; s > 0; s >>= 1) {
        if (tid < s) red[tid] += red[tid + s];
        __syncthreads();
    }
    const int start = red[0];                 // visible: last iter ended with sync
    const int L     = sizes[seg] - w + 1;     // rows to reduce (510 here)

    // ---- strided max over rows; 32 x float4 lanes cover D=128 ----
    const int nc4  = D >> 2;                  // float4s per row (32)
    const int col4 = tid & 31;
    const int rg   = tid >> 5;                // 0..7 row groups

    f32x4 acc = { -INFINITY, -INFINITY, -INFINITY, -INFINITY };

    if (col4 < nc4) {
        const f32x4* base  = (const f32x4*)x + (size_t)start * nc4 + col4;
        const size_t step8 = (size_t)nc4 << 3;          // 8 rows

        // this thread handles rows rg + 8k, k in [0, K)
        const int K  = (L > rg) ? ((L - rg + 7) >> 3) : 0;
        // block-dependent rotation: 64 phases x 4 KiB covers the segment
        const int k0 = ((seg & 63) * K) >> 6;           // in [0, K)

        const f32x4* p = base + (size_t)(rg + (k0 << 3)) * nc4;
        #pragma unroll 4
        for (int k = k0; k < K; ++k) {
            acc = fmax4v(acc, __builtin_nontemporal_load(p));
            p += step8;
        }
        p = base + (size_t)rg * nc4;
        #pragma unroll 4
        for (int k = 0; k < k0; ++k) {
            acc = fmax4v(acc, __builtin_nontemporal_load(p));
            p += step8;
        }
    }

    // ---- reduce the 8 row-group partials via LDS ----
    __shared__ f32x4 part[8][32];
    if (col4 < nc4) part[rg][col4] = acc;
    __syncthreads();

    if (tid < nc4) {
        f32x4 a = part[0][tid];
        #pragma unroll
        for (int j = 1; j < 8; ++j) a = fmax4v(a, part[j][tid]);
        ((f32x4*)out)[(size_t)seg * nc4 + tid] = a;
    }
}

extern "C" void kernel_launch(void* const* d_in, const int* in_sizes, int n_in,
                              void* d_out, int out_size, void* d_ws, size_t ws_size,
                              hipStream_t stream) {
    const float* x     = (const float*)d_in[0];
    const int*   sizes = (const int*)d_in[1];
    const int*   wptr  = (const int*)d_in[2];
    float*       out   = (float*)d_out;

    const int n_seg = in_sizes[1];            // 2048
    const int D     = out_size / n_seg;       // 128

    seg_prefix_max_kernel<<<n_seg, BLOCK, 0, stream>>>(x, sizes, wptr, out, n_seg, D);
}